// Round 10
// baseline (391.858 us; speedup 1.0000x reference)
//
#include <hip/hip_runtime.h>

typedef __attribute__((ext_vector_type(8))) short bf16x8;
typedef __attribute__((ext_vector_type(4))) float f32x4;

__device__ __forceinline__ unsigned int f2bf(float f) {
    union { float f; unsigned int u; } v; v.f = f;
    unsigned int u = v.u;
    u += 0x7FFFu + ((u >> 16) & 1u);   // round-to-nearest-even
    return u >> 16;
}

// Pack lin1_W [256][256] f32 (row-major, W[k][n]) into bf16 MFMA-B-fragment order,
// F-MAJOR: 16B unit index tid = (f*8 + kt)*64 + lane holds
//   { W[kt*32 + (lane>>4)*8 + j][f*16 + (lane&15)] : j = 0..7 }
__global__ void pack_w_kernel(const float* __restrict__ W, unsigned short* __restrict__ P) {
    int tid = blockIdx.x * blockDim.x + threadIdx.x;
    if (tid >= 8192) return;
    int f    = tid >> 9;
    int kt   = (tid >> 6) & 7;
    int lane = tid & 63;
    int k0  = kt * 32 + (lane >> 4) * 8;
    int col = f * 16 + (lane & 15);
    bf16x8 v;
    #pragma unroll
    for (int j = 0; j < 8; ++j)
        v[j] = (short)f2bf(W[(k0 + j) * 256 + col]);
    ((bf16x8*)P)[tid] = v;
}

// Weight-stationary, third attempt — the ONLY change vs R9 is
// __launch_bounds__(1024, 2): empirical hipcc law VGPR_target = 256/N, so
// N=2 -> 128 VGPRs (working set ~100 fits, and 16 waves x 128 = exact HW
// budget so the single block/CU still launches). Body is bit-identical.
__global__ __launch_bounds__(1024, 2)
void fused_kernel(const float* __restrict__ x,
                  const int* __restrict__ samples,
                  const unsigned short* __restrict__ Wp,
                  const float* __restrict__ b1,
                  const float* __restrict__ w2,
                  const float* __restrict__ b2,
                  float* __restrict__ out, int S)
{
    __shared__ bf16x8 wlds[8192];   // 128 KiB = entire packed lin1_W

    const int tid  = threadIdx.x;
    const int lane = tid & 63;
    const int wave = tid >> 6;      // 0..15
    const int cl   = lane & 15;
    const int hi   = lane >> 4;

    // ---- cooperative W -> LDS stage: 128 B per thread, linear, coalesced ----
    const bf16x8* wpv = (const bf16x8*)Wp;
    #pragma unroll
    for (int i = 0; i < 8; ++i) wlds[i * 1024 + tid] = wpv[i * 1024 + tid];
    __syncthreads();                 // the ONLY barrier

    const bf16x8* wl  = wlds + lane;
    const int NT   = (S + 15) >> 4;  // 6250 16-row tiles
    const int imax = 2 * S - 1;

    // wave's tiles: t = blockIdx.x + 256*wave, then +4096 — identical work
    // distribution in every block -> balanced across CUs, no barriers.
    for (int t = (int)blockIdx.x + (wave << 8); t < NT; t += 4096) {
        const int row0 = t << 4;

        // ---- sample indices: one coalesced load + shfl broadcast ----
        int i0   = row0 * 2 + (lane & 31);
        int sidx = samples[i0 < imax ? i0 : imax];
        int ra = __shfl(sidx, 2 * cl,     64);
        int rb = __shfl(sidx, 2 * cl + 1, 64);
        const f32x4* xa = (const f32x4*)x + (size_t)ra * 64;
        const f32x4* xb = (const f32x4*)x + (size_t)rb * 64;

        // ---- direct per-lane A-fragment gather (R5-verified layout) ----
        // af[kt][j] = bf16( x[ra][kt*32+hi*8+j] * x[rb][kt*32+hi*8+j] )
        bf16x8 af[8];
        #pragma unroll
        for (int g = 0; g < 4; ++g) {     // 2 kt per batch: 8 indep. 16B loads
            f32x4 v[8];
            #pragma unroll
            for (int k = 0; k < 2; ++k) {
                int kt = g * 2 + k;
                int o  = kt * 8 + hi * 2;
                v[k*4 + 0] = xa[o];  v[k*4 + 1] = xa[o + 1];
                v[k*4 + 2] = xb[o];  v[k*4 + 3] = xb[o + 1];
            }
            #pragma unroll
            for (int k = 0; k < 2; ++k) {
                int kt = g * 2 + k;
                bf16x8 u;
                #pragma unroll
                for (int j = 0; j < 4; ++j) {
                    u[j]     = (short)f2bf(v[k*4 + 0][j] * v[k*4 + 2][j]);
                    u[4 + j] = (short)f2bf(v[k*4 + 1][j] * v[k*4 + 3][j]);
                }
                af[kt] = u;
            }
        }

        // ---- f-major loop: B-fragment per-kt from LDS (low reg pressure),
        //      fused bias/ReLU/w2 epilogue ----
        float p0[4] = {0.f, 0.f, 0.f, 0.f};
        float p1[4] = {0.f, 0.f, 0.f, 0.f};
        #pragma unroll
        for (int f = 0; f < 16; ++f) {
            f32x4 a4 = (f32x4){0.f, 0.f, 0.f, 0.f};
            #pragma unroll
            for (int kt = 0; kt < 8; ++kt)
                a4 = __builtin_amdgcn_mfma_f32_16x16x32_bf16(af[kt], wl[f * 512 + kt * 64], a4, 0, 0, 0);
            float  b1v = b1[f * 16 + cl];
            float2 lw  = ((const float2*)w2)[f * 16 + cl];
            #pragma unroll
            for (int q = 0; q < 4; ++q) {
                float h = fmaxf(a4[q] + b1v, 0.f);
                p0[q] += h * lw.x;
                p1[q] += h * lw.y;
            }
        }

        // ---- 16-lane shuffle reduce of the [16x2] partials + masked store ----
        #pragma unroll
        for (int m = 1; m < 16; m <<= 1) {
            #pragma unroll
            for (int q = 0; q < 4; ++q) {
                p0[q] += __shfl_xor(p0[q], m, 64);
                p1[q] += __shfl_xor(p1[q], m, 64);
            }
        }
        if (cl < 8) {
            int q = cl >> 1, j = cl & 1;
            int r = row0 + hi * 4 + q;
            if (r < S) {
                float v = (j == 0 ? p0[q] : p1[q]) + b2[j];
                out[r * 2 + j] = v;
            }
        }
    }
}

extern "C" void kernel_launch(void* const* d_in, const int* in_sizes, int n_in,
                              void* d_out, int out_size, void* d_ws, size_t ws_size,
                              hipStream_t stream) {
    // setup_inputs order:
    // 0 x_feature, 1 edge_index(unused), 2 samples, 3 W1(u), 4 b1(u), 5 W2(u), 6 b2(u),
    // 7 lin1_W, 8 lin1_b, 9 lin2_W, 10 lin2_b
    const float* x       = (const float*)d_in[0];
    const int*   samples = (const int*)d_in[2];
    const float* lin1_W  = (const float*)d_in[7];
    const float* lin1_b  = (const float*)d_in[8];
    const float* lin2_W  = (const float*)d_in[9];
    const float* lin2_b  = (const float*)d_in[10];
    float* out = (float*)d_out;

    unsigned short* Wp = (unsigned short*)d_ws;   // 8192 * 16B = 128 KiB packed lin1_W
    const int S = in_sizes[2] / 2;                // 100000 sample pairs

    pack_w_kernel<<<32, 256, 0, stream>>>(lin1_W, Wp);

    // one 1024-thread weight-stationary block per CU
    fused_kernel<<<256, 1024, 0, stream>>>(x, samples, Wp, lin1_b, lin2_W, lin2_b, out, S);
}

// Round 11
// 91.397 us; speedup vs baseline: 4.2874x; 4.2874x over previous
//
#include <hip/hip_runtime.h>

typedef __attribute__((ext_vector_type(8))) short bf16x8;
typedef __attribute__((ext_vector_type(4))) float f32x4;

__device__ __forceinline__ unsigned int f2bf(float f) {
    union { float f; unsigned int u; } v; v.f = f;
    unsigned int u = v.u;
    u += 0x7FFFu + ((u >> 16) & 1u);   // round-to-nearest-even
    return u >> 16;
}

// Pack lin1_W [256][256] f32 (row-major, W[k][n]) into bf16 MFMA-B-fragment order,
// F-MAJOR: 16B unit index tid = (f*8 + kt)*64 + lane holds
//   { W[kt*32 + (lane>>4)*8 + j][f*16 + (lane&15)] : j = 0..7 }
__global__ void pack_w_kernel(const float* __restrict__ W, unsigned short* __restrict__ P) {
    int tid = blockIdx.x * blockDim.x + threadIdx.x;
    if (tid >= 8192) return;
    int f    = tid >> 9;
    int kt   = (tid >> 6) & 7;
    int lane = tid & 63;
    int k0  = kt * 32 + (lane >> 4) * 8;
    int col = f * 16 + (lane & 15);
    bf16x8 v;
    #pragma unroll
    for (int j = 0; j < 8; ++j)
        v[j] = (short)f2bf(W[(k0 + j) * 256 + col]);
    ((bf16x8*)P)[tid] = v;
}

// R7 body (bit-exact validated) at the R2/R3-proven no-spill register point.
// Barrier-free, LDS-FREE, 16 rows/wave, direct per-lane A-fragment gather,
// B streamed from L2-resident Wp with fused f-major epilogue.
// LDS=0 -> up to 8 blocks/CU (32 waves) of latency-hiding TLP.
__global__ __launch_bounds__(256, 4)
void fused_kernel(const float* __restrict__ x,
                  const int* __restrict__ samples,
                  const unsigned short* __restrict__ Wp,
                  const float* __restrict__ b1,
                  const float* __restrict__ w2,
                  const float* __restrict__ b2,
                  float* __restrict__ out, int S)
{
    const int tid  = threadIdx.x;
    const int lane = tid & 63;
    const int wave = tid >> 6;
    const int cl   = lane & 15;
    const int hi   = lane >> 4;
    const int row0 = blockIdx.x * 64 + wave * 16;   // this wave's 16 output rows

    // ---- sample indices: one coalesced load + shfl broadcast ----
    int imax = 2 * S - 1;
    int i0   = row0 * 2 + (lane & 31);
    int sidx = samples[i0 < imax ? i0 : imax];
    int ra = __shfl(sidx, 2 * cl,     64);
    int rb = __shfl(sidx, 2 * cl + 1, 64);
    const f32x4* xa = (const f32x4*)x + (size_t)ra * 64;
    const f32x4* xb = (const f32x4*)x + (size_t)rb * 64;

    // ---- direct per-lane A-fragment gather (R5-verified layout) ----
    // af[kt][j] = bf16( x[ra][kt*32+hi*8+j] * x[rb][kt*32+hi*8+j] ), j=0..7
    bf16x8 af[8];
    #pragma unroll
    for (int g = 0; g < 4; ++g) {        // 2 kt per batch: 8 independent 16B loads
        f32x4 v[8];
        #pragma unroll
        for (int k = 0; k < 2; ++k) {
            int kt = g * 2 + k;
            int o  = kt * 8 + hi * 2;    // f32x4-unit offset of k = kt*32 + hi*8
            v[k*4 + 0] = xa[o];  v[k*4 + 1] = xa[o + 1];
            v[k*4 + 2] = xb[o];  v[k*4 + 3] = xb[o + 1];
        }
        #pragma unroll
        for (int k = 0; k < 2; ++k) {
            int kt = g * 2 + k;
            bf16x8 u;
            #pragma unroll
            for (int j = 0; j < 4; ++j) {
                u[j]     = (short)f2bf(v[k*4 + 0][j] * v[k*4 + 2][j]);
                u[4 + j] = (short)f2bf(v[k*4 + 1][j] * v[k*4 + 3][j]);
            }
            af[kt] = u;
        }
    }

    // ---- f-major W stream from L2 with fused epilogue; no LDS, no barriers ----
    const bf16x8* wgl = (const bf16x8*)Wp + lane;
    float p0[4] = {0.f, 0.f, 0.f, 0.f};
    float p1[4] = {0.f, 0.f, 0.f, 0.f};

    #pragma unroll
    for (int f = 0; f < 16; ++f) {
        bf16x8 bc[8];
        #pragma unroll
        for (int kt = 0; kt < 8; ++kt) bc[kt] = wgl[f * 512 + kt * 64];
        f32x4 a4 = (f32x4){0.f, 0.f, 0.f, 0.f};
        #pragma unroll
        for (int kt = 0; kt < 8; ++kt)
            a4 = __builtin_amdgcn_mfma_f32_16x16x32_bf16(af[kt], bc[kt], a4, 0, 0, 0);
        float  b1v = b1[f * 16 + cl];
        float2 lw  = ((const float2*)w2)[f * 16 + cl];
        #pragma unroll
        for (int q = 0; q < 4; ++q) {
            float h = fmaxf(a4[q] + b1v, 0.f);
            p0[q] += h * lw.x;
            p1[q] += h * lw.y;
        }
    }

    // ---- 16-lane shuffle reduce of the [16x2] partials + store ----
    #pragma unroll
    for (int m = 1; m < 16; m <<= 1) {
        #pragma unroll
        for (int q = 0; q < 4; ++q) {
            p0[q] += __shfl_xor(p0[q], m, 64);
            p1[q] += __shfl_xor(p1[q], m, 64);
        }
    }
    // lanes cl=0..7 of each 16-lane group write 8 consecutive floats (4 rows x 2 cols)
    if (cl < 8) {
        int q = cl >> 1, j = cl & 1;
        int r = row0 + hi * 4 + q;
        if (r < S) {
            float v = (j == 0 ? p0[q] : p1[q]) + b2[j];
            out[r * 2 + j] = v;
        }
    }
}

extern "C" void kernel_launch(void* const* d_in, const int* in_sizes, int n_in,
                              void* d_out, int out_size, void* d_ws, size_t ws_size,
                              hipStream_t stream) {
    // setup_inputs order:
    // 0 x_feature, 1 edge_index(unused), 2 samples, 3 W1(u), 4 b1(u), 5 W2(u), 6 b2(u),
    // 7 lin1_W, 8 lin1_b, 9 lin2_W, 10 lin2_b
    const float* x       = (const float*)d_in[0];
    const int*   samples = (const int*)d_in[2];
    const float* lin1_W  = (const float*)d_in[7];
    const float* lin1_b  = (const float*)d_in[8];
    const float* lin2_W  = (const float*)d_in[9];
    const float* lin2_b  = (const float*)d_in[10];
    float* out = (float*)d_out;

    unsigned short* Wp = (unsigned short*)d_ws;   // 8192 * 16B = 128 KiB packed lin1_W
    const int S = in_sizes[2] / 2;                // 100000 sample pairs

    pack_w_kernel<<<32, 256, 0, stream>>>(lin1_W, Wp);

    const int nblk = (S + 63) / 64;               // 1563 blocks of 64 rows
    fused_kernel<<<nblk, 256, 0, stream>>>(x, samples, Wp, lin1_b, lin2_W, lin2_b, out, S);
}